// Round 8
// baseline (309.296 us; speedup 1.0000x reference)
//
#include <hip/hip_runtime.h>

// LocalityLoss — R8: MEASUREMENT ROUND. R6's exact structure, but the input is
// read TWICE (two full staging passes; accumulators halved at the end — bit-
// identical result). dur(R8) - dur(R6) directly measures the sums kernel's
// load-pass time K, which rocprof top-5 can no longer see (kernel < fill dur).
// Decides between "K~35us, rest is harness floor" and "K~90us, keep pushing".

constexpr int T = 32, C = 512, H = 56, W = 56;
constexpr int HW = H * W;       // 3136
constexpr int PADW = 60;        // row stride 240B: 16B-aligned, breaks pow2 conflicts
constexpr int CPB = 4;          // channels per block, 1 per pipeline round
constexpr float EPS = 1e-6f;

__global__ __launch_bounds__(256) void sums_kernel(const float* __restrict__ x,
                                                   float* __restrict__ part) {
    __shared__ float tile[2][H * PADW];   // 2 x 13.44 KB = 26.9 KB -> 5 blocks/CU
    const int bid = blockIdx.x;
    const int t  = bid >> 7;              // C/CPB == 128 channel-groups
    const int cg = bid & 127;
    const float* base = x + ((size_t)t * C + (size_t)cg * CPB) * HW;

    const int tid  = threadIdx.x;
    const int wave = tid >> 6;
    const int lane = tid & 63;
    const int role = wave & 1;            // 0 = rows (h), 1 = cols (w)
    const int half = wave >> 1;           // k-half (rows) / r-half (cols)

    float a0 = 0.f, a1 = 0.f;             // (sumsq, sum)

    for (int pass = 0; pass < 2; ++pass) {
        // prologue: stage channel 0 into tile[0]
        {
            const float4* src = (const float4*)base;
            #pragma unroll
            for (int i = 0; i < 4; ++i) {
                int idx = tid + i * 256;
                if (idx < 784) {
                    float4 v = src[idx];
                    int h = idx / 14, w = (idx - h * 14) * 4;
                    *(float4*)&tile[0][h * PADW + w] = v;
                }
            }
        }
        __syncthreads();

        #pragma unroll
        for (int c = 1; c <= CPB; ++c) {
            // (1) prefetch channel c into VGPRs (in flight during reduce)
            float4 nxt[4];
            if (c < CPB) {
                const float4* src = (const float4*)(base + (size_t)c * HW);
                #pragma unroll
                for (int i = 0; i < 4; ++i) {
                    int idx = tid + i * 256;
                    nxt[i] = (idx < 784) ? src[idx] : make_float4(0.f, 0.f, 0.f, 0.f);
                }
            }
            // (2) reduce channel c-1 from tile[(c-1)&1]
            const float* tl = tile[(c - 1) & 1];
            if (role == 0) {
                if (lane < H) {
                    const float* rowp = &tl[lane * PADW + half * 28];
                    #pragma unroll
                    for (int k = 0; k < 7; ++k) {
                        float4 v = *(const float4*)&rowp[k * 4];
                        a0 += v.x * v.x + v.y * v.y + v.z * v.z + v.w * v.w;
                        a1 += v.x + v.y + v.z + v.w;
                    }
                }
            } else {
                if (lane < W) {
                    #pragma unroll 7
                    for (int r = half * 28; r < half * 28 + 28; ++r) {
                        float v = tl[r * PADW + lane];
                        a0 += v * v;
                        a1 += v;
                    }
                }
            }
            // (3) commit prefetched data, barrier
            if (c < CPB) {
                #pragma unroll
                for (int i = 0; i < 4; ++i) {
                    int idx = tid + i * 256;
                    if (idx < 784) {
                        int h = idx / 14, w = (idx - h * 14) * 4;
                        *(float4*)&tile[c & 1][h * PADW + w] = nxt[i];
                    }
                }
            }
            __syncthreads();
        }
    }
    a0 *= 0.5f;  // two identical passes -> exact halving
    a1 *= 0.5f;

    // Per-wave partial write, no atomics.
    if (lane < 56) {
        float* wbase = part + (size_t)bid * 448 + (size_t)wave * 112;
        wbase[lane]      = a0;
        wbase[56 + lane] = a1;
    }
}

// One block per image t (512 threads): two thread-groups each sum half the 128
// block-slices for all 224 bins, LDS-combine, then compute the per-t loss.
__global__ __launch_bounds__(512) void reduce_kernel(const float* __restrict__ part,
                                                     float* __restrict__ out) {
    __shared__ float tot2[2][224];
    const int t = blockIdx.x;
    const int tid = threadIdx.x;
    const float* base = part + (size_t)t * 128 * 448;
    if (tid < 448) {
        int g = tid / 224, bin = tid - g * 224;
        float s = 0.f;
        #pragma unroll 8
        for (int b = g * 64; b < g * 64 + 64; ++b) {
            s += base[b * 448 + bin];        // waves 0,1
            s += base[b * 448 + 224 + bin];  // waves 2,3
        }
        tot2[g][bin] = s;
    }
    __syncthreads();
    if (tid < 2) {
        // tid 0: rows (h axis); tid 1: cols (w axis)
        const float n_other = 28672.0f;  // 512*56 for both axes
        const int o = tid * 112;
        float loss = 0.f;
        float psq = 0.f, plin = 0.f, ssq = 0.f, slin = 0.f;
        for (int i = 0; i < 56; ++i) {
            float sqi  = tot2[0][o + i]       + tot2[1][o + i];
            float lini = tot2[0][o + 56 + i]  + tot2[1][o + 56 + i];
            float sqj  = tot2[0][o + 55 - i]      + tot2[1][o + 55 - i];
            float linj = tot2[0][o + 56 + 55 - i] + tot2[1][o + 56 + 55 - i];
            psq += sqi; plin += lini; ssq += sqj; slin += linj;
            float n = n_other * (float)(i + 1);
            loss += sqrtf(psq + 2.f * EPS * plin + EPS * EPS * n) + EPS;  // prefix
            loss += sqrtf(ssq + 2.f * EPS * slin + EPS * EPS * n) + EPS;  // suffix
        }
        atomicAdd(out, loss * (1.0f / 128.0f));  // /4 losses, /32 mean over t
    }
}

extern "C" void kernel_launch(void* const* d_in, const int* in_sizes, int n_in,
                              void* d_out, int out_size, void* d_ws, size_t ws_size,
                              hipStream_t stream) {
    const float* x = (const float*)d_in[0];
    float* out = (float*)d_out;
    float* part = (float*)d_ws;  // 4096 blocks x 448 floats = 7.34 MB

    hipMemsetAsync(out, 0, sizeof(float), stream);
    sums_kernel<<<T * (C / CPB), 256, 0, stream>>>(x, part);
    reduce_kernel<<<T, 512, 0, stream>>>(part, out);
}

// Round 9
// 291.097 us; speedup vs baseline: 1.0625x; 1.0625x over previous
//
#include <hip/hip_runtime.h>

// LocalityLoss: all four losses reduce to per-(t,h) and per-(t,w) sums of x and
// x^2 over the other axes (n_other = 512*56 = 28672), then prefix/suffix
// cumsums of 56 values per image.
//
// R9 == R6 (best, 293.3 us), reinstated after R8's measurement round.
// R8 (input read twice, otherwise identical) cost +16.0 us -> one full 205.5 MB
// input pass runs at ~12.8 TB/s (L3-resident; harness's input-restore keeps it
// warm). So this kernel's total cost is ~20-30 us; the remaining ~268 us of
// dur_us is harness reset (822 MB ws-poison fill ~120 us + input restore
// ~65 us + dispatch overhead) — not controllable from kernel_launch.
//
// Structure: CPB=4 -> 4096 blocks (16/CU queued). Per round: prefetch next
// channel into VGPRs, reduce current channel from LDS (all 4 waves: rows split
// by k-half, cols by r-half), commit prefetch to the other LDS tile, barrier.
// No global atomics in the hot kernel (R3/R4 proved memory-side fp32 atomics
// serialize at ~9 lane-ops/ns); per-wave partials + tiny per-t reduce instead.

constexpr int T = 32, C = 512, H = 56, W = 56;
constexpr int HW = H * W;       // 3136
constexpr int PADW = 60;        // row stride 240B: 16B-aligned, breaks pow2 conflicts
constexpr int CPB = 4;          // channels per block, 1 per pipeline round
constexpr float EPS = 1e-6f;

__global__ __launch_bounds__(256) void sums_kernel(const float* __restrict__ x,
                                                   float* __restrict__ part) {
    __shared__ float tile[2][H * PADW];   // 2 x 13.44 KB = 26.9 KB -> 5 blocks/CU
    const int bid = blockIdx.x;
    const int t  = bid >> 7;              // C/CPB == 128 channel-groups
    const int cg = bid & 127;
    const float* base = x + ((size_t)t * C + (size_t)cg * CPB) * HW;

    const int tid  = threadIdx.x;
    const int wave = tid >> 6;
    const int lane = tid & 63;
    const int role = wave & 1;            // 0 = rows (h), 1 = cols (w)
    const int half = wave >> 1;           // k-half (rows) / r-half (cols)

    float a0 = 0.f, a1 = 0.f;             // (sumsq, sum)

    // prologue: stage channel 0 into tile[0]
    {
        const float4* src = (const float4*)base;
        #pragma unroll
        for (int i = 0; i < 4; ++i) {
            int idx = tid + i * 256;
            if (idx < 784) {
                float4 v = src[idx];
                int h = idx / 14, w = (idx - h * 14) * 4;
                *(float4*)&tile[0][h * PADW + w] = v;
            }
        }
    }
    __syncthreads();

    #pragma unroll
    for (int c = 1; c <= CPB; ++c) {
        // (1) prefetch channel c into VGPRs (in flight during reduce)
        float4 nxt[4];
        if (c < CPB) {
            const float4* src = (const float4*)(base + (size_t)c * HW);
            #pragma unroll
            for (int i = 0; i < 4; ++i) {
                int idx = tid + i * 256;
                nxt[i] = (idx < 784) ? src[idx] : make_float4(0.f, 0.f, 0.f, 0.f);
            }
        }
        // (2) reduce channel c-1 from tile[(c-1)&1]
        const float* tl = tile[(c - 1) & 1];
        if (role == 0) {
            if (lane < H) {
                const float* rowp = &tl[lane * PADW + half * 28];
                #pragma unroll
                for (int k = 0; k < 7; ++k) {
                    float4 v = *(const float4*)&rowp[k * 4];
                    a0 += v.x * v.x + v.y * v.y + v.z * v.z + v.w * v.w;
                    a1 += v.x + v.y + v.z + v.w;
                }
            }
        } else {
            if (lane < W) {
                #pragma unroll 7
                for (int r = half * 28; r < half * 28 + 28; ++r) {
                    float v = tl[r * PADW + lane];
                    a0 += v * v;
                    a1 += v;
                }
            }
        }
        // (3) commit prefetched data, barrier
        if (c < CPB) {
            #pragma unroll
            for (int i = 0; i < 4; ++i) {
                int idx = tid + i * 256;
                if (idx < 784) {
                    int h = idx / 14, w = (idx - h * 14) * 4;
                    *(float4*)&tile[c & 1][h * PADW + w] = nxt[i];
                }
            }
        }
        __syncthreads();
    }

    // Per-wave partial write, no atomics.
    // Block slice (448 floats): [w0 rows sq|lin][w1 cols sq|lin][w2 rows][w3 cols]
    if (lane < 56) {
        float* wbase = part + (size_t)bid * 448 + (size_t)wave * 112;
        wbase[lane]      = a0;
        wbase[56 + lane] = a1;
    }
}

// One block per image t (512 threads): two thread-groups each sum half the 128
// block-slices for all 224 bins, LDS-combine, then compute the per-t loss.
__global__ __launch_bounds__(512) void reduce_kernel(const float* __restrict__ part,
                                                     float* __restrict__ out) {
    __shared__ float tot2[2][224];
    const int t = blockIdx.x;
    const int tid = threadIdx.x;
    const float* base = part + (size_t)t * 128 * 448;
    if (tid < 448) {
        int g = tid / 224, bin = tid - g * 224;
        float s = 0.f;
        #pragma unroll 8
        for (int b = g * 64; b < g * 64 + 64; ++b) {
            s += base[b * 448 + bin];        // waves 0,1
            s += base[b * 448 + 224 + bin];  // waves 2,3
        }
        tot2[g][bin] = s;
    }
    __syncthreads();
    if (tid < 2) {
        // tid 0: rows (h axis); tid 1: cols (w axis)
        const float n_other = 28672.0f;  // 512*56 for both axes
        const int o = tid * 112;
        float loss = 0.f;
        float psq = 0.f, plin = 0.f, ssq = 0.f, slin = 0.f;
        for (int i = 0; i < 56; ++i) {
            float sqi  = tot2[0][o + i]       + tot2[1][o + i];
            float lini = tot2[0][o + 56 + i]  + tot2[1][o + 56 + i];
            float sqj  = tot2[0][o + 55 - i]      + tot2[1][o + 55 - i];
            float linj = tot2[0][o + 56 + 55 - i] + tot2[1][o + 56 + 55 - i];
            psq += sqi; plin += lini; ssq += sqj; slin += linj;
            float n = n_other * (float)(i + 1);
            loss += sqrtf(psq + 2.f * EPS * plin + EPS * EPS * n) + EPS;  // prefix
            loss += sqrtf(ssq + 2.f * EPS * slin + EPS * EPS * n) + EPS;  // suffix
        }
        atomicAdd(out, loss * (1.0f / 128.0f));  // /4 losses, /32 mean over t
    }
}

extern "C" void kernel_launch(void* const* d_in, const int* in_sizes, int n_in,
                              void* d_out, int out_size, void* d_ws, size_t ws_size,
                              hipStream_t stream) {
    const float* x = (const float*)d_in[0];
    float* out = (float*)d_out;
    float* part = (float*)d_ws;  // 4096 blocks x 448 floats = 7.34 MB

    hipMemsetAsync(out, 0, sizeof(float), stream);
    sums_kernel<<<T * (C / CPB), 256, 0, stream>>>(x, part);
    reduce_kernel<<<T, 512, 0, stream>>>(part, out);
}